// Round 14
// baseline (280.585 us; speedup 1.0000x reference)
//
#include <hip/hip_runtime.h>
#include <hip/hip_bf16.h>
#include <math.h>

// ---------------------------------------------------------------------------
// GINE model: 3x (GINEConv + BN + ReLU) -> global mean pool -> MLP -> sigmoid
// Round 14: 2 tiles/wave in the edge kernel (prologue amortization), launch
// fusion (hist+wxprep merged; scan_mid folded into scan_out; 12 dispatches),
// pool_head w4 pre-permuted row-major for float4 streaming.
// ---------------------------------------------------------------------------

typedef __attribute__((ext_vector_type(8))) short short8v;
typedef __attribute__((ext_vector_type(4))) float f32x4;
typedef __attribute__((ext_vector_type(4))) unsigned short us4;
typedef __attribute__((ext_vector_type(8))) unsigned short us8;

static __device__ __forceinline__ float bf2f(unsigned short u) {
    union { unsigned int u32; float f; } c; c.u32 = ((unsigned int)u) << 16; return c.f;
}
static __device__ __forceinline__ unsigned short f2bf(float f) {
    union { float f; unsigned int u; } c; c.f = f;
    unsigned int lsb = (c.u >> 16) & 1u;
    c.u += 0x7fffu + lsb;
    return (unsigned short)(c.u >> 16);
}

__global__ void k_zero_i(int* __restrict__ p, int n) {
    int i = blockIdx.x * blockDim.x + threadIdx.x;
    int st = gridDim.x * blockDim.x;
    for (; i < n; i += st) p[i] = 0;
}

// merged: dst histogram (blocks 0..511), batch histogram (512..639),
// weight/x prep (blocks 640..)
__global__ void k_pre1(const int* __restrict__ dst, int E,
                       const int* __restrict__ batch, int N,
                       int* __restrict__ ideg, int* __restrict__ gcnt,
                       const float* __restrict__ we1, const float* __restrict__ we2,
                       const float* __restrict__ we3, const float* __restrict__ wn1,
                       const float* __restrict__ wn2, const float* __restrict__ wn3,
                       const float* __restrict__ w4, const float* __restrict__ x,
                       unsigned short* __restrict__ webf1, unsigned short* __restrict__ webf2,
                       unsigned short* __restrict__ webf3, unsigned short* __restrict__ wnbf1,
                       unsigned short* __restrict__ wnbf2, unsigned short* __restrict__ wnbf3,
                       float* __restrict__ w4p, unsigned short* __restrict__ x_bf,
                       float* __restrict__ aggrA, int n16) {
    int b = blockIdx.x;
    if (b < 512) {
        int i = b * 256 + threadIdx.x, st = 512 * 256;
        for (; i < E; i += st) atomicAdd(&ideg[dst[i]], 1);
        return;
    }
    if (b < 640) {
        int i = (b - 512) * 256 + threadIdx.x, st = 128 * 256;
        for (; i < N; i += st) atomicAdd(&gcnt[batch[i]], 1);
        return;
    }
    int idx = (b - 640) * 256 + threadIdx.x;
    if (idx >= 49664) {
        int i = idx - 49664;
        if (i < n16) {
            int n = i >> 4, j = i & 15;
            float4 t = *(const float4*)(x + (size_t)n * 64 + j * 4);
            ((float4*)aggrA)[i] = t;
            us4 o;
            o.x = f2bf(x[(size_t)n * 64 + j]);
            o.y = f2bf(x[(size_t)n * 64 + 16 + j]);
            o.z = f2bf(x[(size_t)n * 64 + 32 + j]);
            o.w = f2bf(x[(size_t)n * 64 + 48 + j]);
            *(us4*)(x_bf + (size_t)n * 64 + j * 4) = o;
        }
        return;
    }
    const float* s; unsigned short* d; int rel;
    if (idx < 512)        { s = we1; d = webf1; rel = idx; }
    else if (idx < 2560)  { s = we2; d = webf2; rel = idx - 512; }
    else if (idx < 4608)  { s = we3; d = webf3; rel = idx - 2560; }
    else if (idx < 8704)  { s = wn1; d = wnbf1; rel = idx - 4608; }
    else if (idx < 25088) { s = wn2; d = wnbf2; rel = idx - 8704; }
    else if (idx < 41472) { s = wn3; d = wnbf3; rel = idx - 25088; }
    else {
        // w4p[j][k] = w4[j][chan(k)]  (row-major, permuted k)
        int rel2 = idx - 41472;            // [0, 8192)
        int j = rel2 >> 6;
        int k0 = (rel2 & 63) * 4;
        float4 o;
        float vv[4];
#pragma unroll
        for (int i = 0; i < 4; ++i) {
            int k = k0 + i;
            int ck = (k & 0xC0) | (((k & 3) * 16) + ((k & 63) >> 2));
            vv[i] = w4[j * 256 + ck];
        }
        o.x = vv[0]; o.y = vv[1]; o.z = vv[2]; o.w = vv[3];
        *(float4*)(w4p + j * 256 + k0) = o;
        return;
    }
    float4 t = ((const float4*)s)[rel];
    us4 o; o.x = f2bf(t.x); o.y = f2bf(t.y); o.z = f2bf(t.z); o.w = f2bf(t.w);
    ((us4*)d)[rel] = o;
}

// per-block sums of ideg
__global__ __launch_bounds__(256) void k_scan_part(const int* __restrict__ in,
                                                   int* __restrict__ part, int n) {
    __shared__ int wtot[4];
    const int tid = threadIdx.x, lane = tid & 63, wv = tid >> 6;
    int i = blockIdx.x * 256 + tid;
    int s = (i < n) ? in[i] : 0;
#pragma unroll
    for (int off = 1; off < 64; off <<= 1) s += __shfl_xor(s, off);
    if (lane == 0) wtot[wv] = s;
    __syncthreads();
    if (tid == 0) part[blockIdx.x] = wtot[0] + wtot[1] + wtot[2] + wtot[3];
}

// blocks 0..npart-1: cursor = exclusive scan of ideg (block offset computed
// in-block from part[]); block npart: gptr = exclusive scan of gcnt (1 wave).
__global__ __launch_bounds__(256) void k_scan_out(const int* __restrict__ in,
                                                  const int* __restrict__ part,
                                                  int* __restrict__ cursor, int n, int npart,
                                                  const int* __restrict__ gcnt,
                                                  int* __restrict__ gptr, int G) {
    const int tid = threadIdx.x, lane = tid & 63, wv = tid >> 6;
    if ((int)blockIdx.x == npart) {
        if (tid < 64) {
            int run = 0;
            for (int c = 0; c < G; c += 64) {
                int v = gcnt[c + lane];
                int s = v;
#pragma unroll
                for (int off = 1; off < 64; off <<= 1) {
                    int t = __shfl_up(s, off);
                    if (lane >= off) s += t;
                }
                gptr[c + lane] = run + s - v;
                run += __shfl(s, 63);
            }
            if (lane == 0) gptr[G] = run;
        }
        return;
    }
    __shared__ int wtot[4];
    const int bid = blockIdx.x;
    // block offset = sum part[0..bid)
    int p = 0;
    if (lane < bid) p = part[lane];
    if (lane + 64 < bid) p += part[lane + 64];     // npart <= 128
#pragma unroll
    for (int off = 1; off < 64; off <<= 1) p += __shfl_xor(p, off);
    int i = bid * 256 + tid;
    int v = (i < n) ? in[i] : 0;
    int s = v;
#pragma unroll
    for (int off = 1; off < 64; off <<= 1) {
        int t = __shfl_up(s, off);
        if (lane >= off) s += t;
    }
    if (lane == 63) wtot[wv] = s;
    __syncthreads();
    int woff = 0;
    for (int k = 0; k < wv; ++k) woff += wtot[k];
    if (i < n) cursor[i] = p + woff + s - v;
}

// bucket edges by dst; convert+write ea row at pos (fused permute); pad tails
__global__ void k_scatter(const int* __restrict__ ei, const float* __restrict__ ea,
                          int E, int Epad, int* __restrict__ cursor,
                          int* __restrict__ esrc_s, int* __restrict__ dst_s,
                          unsigned short* __restrict__ ea_s) {
    int i = blockIdx.x * blockDim.x + threadIdx.x;
    int st = gridDim.x * blockDim.x;
    for (int k = i; k < E; k += st) {
        int d = ei[E + k];
        int pos = atomicAdd(&cursor[d], 1);
        esrc_s[pos] = ei[k];
        dst_s[pos] = d;
        const float4* sp = (const float4*)(ea + (size_t)k * 32);
        unsigned short* dp = ea_s + (size_t)pos * 32;
#pragma unroll
        for (int h = 0; h < 4; ++h) {
            float4 a = sp[2 * h], b = sp[2 * h + 1];
            us8 o;
            o[0] = f2bf(a.x); o[1] = f2bf(a.y); o[2] = f2bf(a.z); o[3] = f2bf(a.w);
            o[4] = f2bf(b.x); o[5] = f2bf(b.y); o[6] = f2bf(b.z); o[7] = f2bf(b.w);
            *(us8*)(dp + h * 8) = o;
        }
    }
    if (i < Epad + 64 - E) {
        dst_s[E + i] = -1;
        if (i < Epad - E) {
            esrc_s[E + i] = 0;
            us4 z = {0, 0, 0, 0};
            us4* p = (us4*)(ea_s + (size_t)(E + i) * 32);
#pragma unroll
            for (int q = 0; q < 8; ++q) p[q] = z;
        }
    }
}

// ---------------------------------------------------------------------------
// Edge kernel (2 consecutive 64-edge tiles per wave). Permuted-h 8B gathers;
// tile-wide inclusive prefix; scalar segment walk with telescoping diff;
// 4 contiguous atomics per segment from lhi==0 lanes.
// aggr must be pre-initialized with the self term (f32, natural layout).
// ---------------------------------------------------------------------------
template<int D>
__global__ __launch_bounds__(256) void k_edge_mfma(
    const unsigned short* __restrict__ hbf,   // [N][D] bf16, PERMUTED layout
    const unsigned short* __restrict__ ea_s,  // [Epad][32] bf16, CSR order
    const int* __restrict__ esrc_s,           // [Epad]
    const int* __restrict__ dst_s,            // [Epad+64], tail = -1
    const unsigned short* __restrict__ webf,  // [D][32] bf16, natural rows
    const float* __restrict__ be,             // [D]
    float* __restrict__ aggr,                 // [N][D] f32, natural layout
    int E)
{
    const int tid = threadIdx.x;
    const int lane = tid & 63;
    const int w = tid >> 6;
    const int l15 = lane & 15;
    const int lhi = lane >> 4;

    const int tbase   = (D == 256) ? ((int)blockIdx.x * 2) : (((int)blockIdx.x * 4 + w) * 2);
    const int colbase = (D == 256) ? (w * 64) : 0;
    if (tbase * 64 >= E) return;

    // persistent B fragments + bias (channel c = colbase + t*16 + l15)
    short8v bfr[4]; float bias[4];
#pragma unroll
    for (int t = 0; t < 4; ++t) {
        int c = colbase + t * 16 + l15;
        bfr[t] = *(const short8v*)(webf + (size_t)c * 32 + lhi * 8);
        bias[t] = be[c];
    }

    for (int tt = 0; tt < 2; ++tt) {
        const int e0 = (tbase + tt) * 64;
        if (e0 >= E) break;

        const int dstreg = dst_s[e0 + lane];      // lane = row

        int4 src4[4];
#pragma unroll
        for (int q = 0; q < 4; ++q)
            src4[q] = *(const int4*)(esrc_s + e0 + q * 16 + lhi * 4);

        short8v afr[4];
#pragma unroll
        for (int q = 0; q < 4; ++q)
            afr[q] = *(const short8v*)(ea_s + (size_t)(e0 + q * 16 + l15) * 32 + lhi * 8);

        // permuted h-gather: one us4 per fragment row -> channels {t*16+l15}
        us4 hv[4][4];
#pragma unroll
        for (int q = 0; q < 4; ++q) {
            const int sr[4] = {src4[q].x, src4[q].y, src4[q].z, src4[q].w};
#pragma unroll
            for (int i = 0; i < 4; ++i)
                hv[q][i] = *(const us4*)(hbf + (size_t)sr[i] * D + colbase + l15 * 4);
        }

        f32x4 acc[4][4];
#pragma unroll
        for (int q = 0; q < 4; ++q)
#pragma unroll
            for (int t = 0; t < 4; ++t) {
                f32x4 ci; ci[0] = bias[t]; ci[1] = bias[t]; ci[2] = bias[t]; ci[3] = bias[t];
                acc[q][t] = __builtin_amdgcn_mfma_f32_16x16x32_bf16(afr[q], bfr[t], ci, 0, 0, 0);
            }

        // m = relu(el + h_src)
#pragma unroll
        for (int q = 0; q < 4; ++q)
#pragma unroll
            for (int i = 0; i < 4; ++i) {
                us4 h4 = hv[q][i];
#pragma unroll
                for (int t = 0; t < 4; ++t)
                    acc[q][t][i] = fmaxf(acc[q][t][i] + bf2f(h4[t]), 0.0f);
            }

        // ---- tile-wide inclusive prefix (in place on acc) ----
        float carry[4] = {0.0f, 0.0f, 0.0f, 0.0f};
#pragma unroll
        for (int q = 0; q < 4; ++q)
#pragma unroll
            for (int t = 0; t < 4; ++t) {
                acc[q][t][1] += acc[q][t][0];
                acc[q][t][2] += acc[q][t][1];
                acc[q][t][3] += acc[q][t][2];
                float g = acc[q][t][3];
                float g1 = __shfl_up(g, 16);
                if (lhi >= 1) g += g1;
                float g2 = __shfl_up(g, 32);
                if (lhi >= 2) g += g2;
                float tqv = __shfl(g, 48 + l15);        // subtile total
                float excl = g - acc[q][t][3] + carry[t];
                acc[q][t][0] += excl; acc[q][t][1] += excl;
                acc[q][t][2] += excl; acc[q][t][3] += excl;
                carry[t] += tqv;
            }

        // ---- segment-end mask (row = lane; forced end at row 63) ----
        int dnext = __shfl_down(dstreg, 1);
        bool endf = (lane == 63) || (dstreg != dnext);
        unsigned long long mask = __ballot(endf);

        // ---- scalar segment walk with telescoping difference ----
        float prevP[4] = {0.0f, 0.0f, 0.0f, 0.0f};
        while (mask) {
            int r = __builtin_amdgcn_readfirstlane((int)__builtin_ctzll(mask));
            mask &= mask - 1;
            int dseg = __shfl(dstreg, r);
            int sl = ((r >> 2) & 3) * 16 + l15;     // source lane holding row r
            float curP[4];
            switch (((r >> 4) << 2) | (r & 3)) {
#define CASE_QI(Q, I) \
                case ((Q) * 4 + (I)): \
                    curP[0] = __shfl(acc[Q][0][I], sl); curP[1] = __shfl(acc[Q][1][I], sl); \
                    curP[2] = __shfl(acc[Q][2][I], sl); curP[3] = __shfl(acc[Q][3][I], sl); \
                    break;
                CASE_QI(0,0) CASE_QI(0,1) CASE_QI(0,2) CASE_QI(0,3)
                CASE_QI(1,0) CASE_QI(1,1) CASE_QI(1,2) CASE_QI(1,3)
                CASE_QI(2,0) CASE_QI(2,1) CASE_QI(2,2) CASE_QI(2,3)
                CASE_QI(3,0) CASE_QI(3,1) CASE_QI(3,2) CASE_QI(3,3)
#undef CASE_QI
            }
            if (dseg >= 0 && lhi == 0) {
                float* base = aggr + (size_t)dseg * D + colbase + l15;
#pragma unroll
                for (int t = 0; t < 4; ++t)
                    atomicAdd(base + t * 16, curP[t] - prevP[t]);
            }
#pragma unroll
            for (int t = 0; t < 4; ++t) prevP[t] = curP[t];
        }
    }
}

// ---------------------------------------------------------------------------
// MFMA node GEMM + BN + ReLU. Natural aggr in/out; h_bf stored PERMUTED via
// two 16B stores per row-fragment.
// ---------------------------------------------------------------------------
template<int K, bool AW>
__global__ __launch_bounds__(256) void k_node_mfma(
    const float* __restrict__ A, const unsigned short* __restrict__ wnbf,
    const float* __restrict__ bnb, const float* __restrict__ g,
    const float* __restrict__ b, const float* __restrict__ rm,
    const float* __restrict__ rv, unsigned short* __restrict__ out,
    float* __restrict__ aggr_out, int N)
{
    const int tid = threadIdx.x;
    const int lane = tid & 63;
    const int w = tid >> 6;
    const int l15 = lane & 15;
    const int lhi = lane >> 4;
    const int row0 = blockIdx.x * 64;
    const int ncol0 = w * 64;

    f32x4 scale[4], shift[4];
    f32x4 acc[4][4];
#pragma unroll
    for (int q = 0; q < 4; ++q) {
        int n0 = ncol0 + q * 16 + lhi * 4;
        float4 gg = *(const float4*)(g + n0);
        float4 rvv = *(const float4*)(rv + n0);
        float4 bb = *(const float4*)(b + n0);
        float4 rmm = *(const float4*)(rm + n0);
        float4 bn = *(const float4*)(bnb + n0);
        f32x4 sc, sh, ci;
        sc[0] = gg.x * rsqrtf(rvv.x + 1e-5f);
        sc[1] = gg.y * rsqrtf(rvv.y + 1e-5f);
        sc[2] = gg.z * rsqrtf(rvv.z + 1e-5f);
        sc[3] = gg.w * rsqrtf(rvv.w + 1e-5f);
        sh[0] = bb.x - rmm.x * sc[0];
        sh[1] = bb.y - rmm.y * sc[1];
        sh[2] = bb.z - rmm.z * sc[2];
        sh[3] = bb.w - rmm.w * sc[3];
        ci[0] = bn.x; ci[1] = bn.y; ci[2] = bn.z; ci[3] = bn.w;
        scale[q] = sc; shift[q] = sh;
#pragma unroll
        for (int r = 0; r < 4; ++r) acc[q][r] = ci;
    }

    for (int k0 = 0; k0 < K; k0 += 32) {
        short8v wfr[4];
#pragma unroll
        for (int q = 0; q < 4; ++q)
            wfr[q] = *(const short8v*)(wnbf + (size_t)(ncol0 + q * 16 + l15) * K + k0 + lhi * 8);
        short8v afr[4];
#pragma unroll
        for (int r = 0; r < 4; ++r) {
            const float* ap = A + (size_t)(row0 + r * 16 + l15) * K + k0 + lhi * 8;
            float4 a0 = ((const float4*)ap)[0];
            float4 a1 = ((const float4*)ap)[1];
            short8v t;
            t[0] = (short)f2bf(a0.x); t[1] = (short)f2bf(a0.y);
            t[2] = (short)f2bf(a0.z); t[3] = (short)f2bf(a0.w);
            t[4] = (short)f2bf(a1.x); t[5] = (short)f2bf(a1.y);
            t[6] = (short)f2bf(a1.z); t[7] = (short)f2bf(a1.w);
            afr[r] = t;
        }
#pragma unroll
        for (int q = 0; q < 4; ++q)
#pragma unroll
            for (int r = 0; r < 4; ++r)
                acc[q][r] = __builtin_amdgcn_mfma_f32_16x16x32_bf16(wfr[q], afr[r], acc[q][r], 0, 0, 0);
    }

#pragma unroll
    for (int r = 0; r < 4; ++r) {
        int m = row0 + r * 16 + l15;
        if (m < N) {
            f32x4 o4[4];
#pragma unroll
            for (int q = 0; q < 4; ++q) {
                int n0 = ncol0 + q * 16 + lhi * 4;
                f32x4 v = acc[q][r];
                f32x4 o;
#pragma unroll
                for (int i = 0; i < 4; ++i)
                    o[i] = fmaxf(v[i] * scale[q][i] + shift[q][i], 0.0f);
                o4[q] = o;
                if (AW) *(f32x4*)(aggr_out + (size_t)m * 256 + n0) = o;
            }
            us8 lo, hi;
#pragma unroll
            for (int q = 0; q < 4; ++q)
#pragma unroll
                for (int i = 0; i < 4; ++i) {
                    int p = i * 4 + q;
                    unsigned short v = f2bf(o4[q][i]);
                    if (p < 8) lo[p] = v; else hi[p - 8] = v;
                }
            *(us8*)(out + (size_t)m * 256 + ncol0 + lhi * 16) = lo;
            *(us8*)(out + (size_t)m * 256 + ncol0 + lhi * 16 + 8) = hi;
        }
    }
}

// Fused global-mean-pool + MLP head (h in PERMUTED bf16; w4p row-major
// with permuted k, so thread j streams its own row with float4).
__global__ __launch_bounds__(256) void k_pool_head(
    const unsigned short* __restrict__ h, const int* __restrict__ gptr,
    const float* __restrict__ w4p, const float* __restrict__ b4,
    const float* __restrict__ w5, const float* __restrict__ b5,
    float* __restrict__ out)
{
    __shared__ float pl[256];
    __shared__ float zs[128];
    const int g = blockIdx.x;
    const int tid = threadIdx.x;
    int beg = gptr[g], end = gptr[g + 1];
    float acc = 0.0f;
    for (int r = beg; r < end; ++r) acc += bf2f(h[(size_t)r * 256 + tid]);
    float cnt = (float)(end - beg);
    pl[tid] = acc / fmaxf(cnt, 1.0f);
    __syncthreads();
    if (tid < 128) {
        float a = b4[tid];
        const float4* wr = (const float4*)(w4p + (size_t)tid * 256);
        for (int k4 = 0; k4 < 64; ++k4) {
            float4 wv = wr[k4];
            int k = k4 * 4;
            a += pl[k] * wv.x + pl[k + 1] * wv.y + pl[k + 2] * wv.z + pl[k + 3] * wv.w;
        }
        zs[tid] = fmaxf(a, 0.0f);
    }
    __syncthreads();
    if (tid < 64) {
        float v = zs[tid] * w5[tid] + zs[tid + 64] * w5[tid + 64];
#pragma unroll
        for (int off = 32; off > 0; off >>= 1) v += __shfl_down(v, off);
        if (tid == 0) out[g] = 1.0f / (1.0f + expf(-(v + b5[0])));
    }
}

extern "C" void kernel_launch(void* const* d_in, const int* in_sizes, int n_in,
                              void* d_out, int out_size, void* d_ws, size_t ws_size,
                              hipStream_t stream)
{
    const float* x    = (const float*)d_in[0];
    const int*   ei   = (const int*)d_in[1];
    const float* ea   = (const float*)d_in[2];
    const int*   batch= (const int*)d_in[3];
    const float* we1  = (const float*)d_in[4];
    const float* be1  = (const float*)d_in[5];
    const float* wn1  = (const float*)d_in[6];
    const float* bnb1 = (const float*)d_in[7];
    const float* we2  = (const float*)d_in[8];
    const float* be2  = (const float*)d_in[9];
    const float* wn2  = (const float*)d_in[10];
    const float* bnb2 = (const float*)d_in[11];
    const float* we3  = (const float*)d_in[12];
    const float* be3  = (const float*)d_in[13];
    const float* wn3  = (const float*)d_in[14];
    const float* bnb3 = (const float*)d_in[15];
    const float* g1 = (const float*)d_in[16];
    const float* b1 = (const float*)d_in[17];
    const float* rm1= (const float*)d_in[18];
    const float* rv1= (const float*)d_in[19];
    const float* g2 = (const float*)d_in[20];
    const float* b2 = (const float*)d_in[21];
    const float* rm2= (const float*)d_in[22];
    const float* rv2= (const float*)d_in[23];
    const float* g3 = (const float*)d_in[24];
    const float* b3 = (const float*)d_in[25];
    const float* rm3= (const float*)d_in[26];
    const float* rv3= (const float*)d_in[27];
    const float* w4 = (const float*)d_in[28];
    const float* b4 = (const float*)d_in[29];
    const float* w5 = (const float*)d_in[30];
    const float* b5 = (const float*)d_in[31];

    const int N = in_sizes[0] / 64;
    const int E = in_sizes[1] / 2;
    const int G = out_size;
    const int Epad = (E + 63) & ~63;
    const int npart = (N + 255) / 256;
    const int n16 = N * 16;

    // ---- workspace layout ----
    float* ws    = (float*)d_ws;
    float* aggrA = ws;                                  // N*256 f32
    float* aggrB = aggrA + (size_t)N * 256;             // N*256 f32
    float* w4p   = aggrB + (size_t)N * 256;             // 128*256
    unsigned short* ea_s  = (unsigned short*)(w4p + 128 * 256);   // Epad*32 bf16
    unsigned short* x_bf  = ea_s + (size_t)Epad * 32;   // N*64 bf16 (permuted)
    unsigned short* h_bf  = x_bf + (size_t)N * 64;      // N*256 bf16 (permuted)
    unsigned short* webf1 = h_bf + (size_t)N * 256;     // 64*32 bf16
    unsigned short* webf2 = webf1 + 64 * 32;            // 256*32
    unsigned short* webf3 = webf2 + 256 * 32;           // 256*32
    unsigned short* wnbf1 = webf3 + 256 * 32;           // 256*64 bf16
    unsigned short* wnbf2 = wnbf1 + 256 * 64;           // 256*256
    unsigned short* wnbf3 = wnbf2 + 256 * 256;          // 256*256
    int* iws    = (int*)(wnbf3 + 256 * 256);
    int* ideg   = iws;                                  // N   (gcnt adjacent!)
    int* gcnt   = ideg + N;                             // G
    int* gptr   = gcnt + G;                             // G+16
    int* cursor = gptr + G + 16;                        // N
    int* esrc_s = cursor + N;                           // Epad
    int* dst_s  = esrc_s + Epad;                        // Epad+64 (tail -1)
    int* part   = dst_s + Epad + 64;                    // npart

    const int nblk64  = (N + 63) / 64;
    const int ntiles  = (E + 63) / 64;
    const int eblk256 = (ntiles + 1) / 2;               // 2 tiles per block
    const int eblk64  = (ntiles + 7) / 8;               // 2 tiles per wave, 4 waves

    // ---- fused preprocessing (5 launches) ----
    k_zero_i<<<64, 256, 0, stream>>>(ideg, N + G);
    k_pre1<<<640 + (49664 + n16 + 255) / 256, 256, 0, stream>>>(
        ei + E, E, batch, N, ideg, gcnt,
        we1, we2, we3, wn1, wn2, wn3, w4, x,
        webf1, webf2, webf3, wnbf1, wnbf2, wnbf3, w4p, x_bf, aggrA, n16);
    k_scan_part<<<npart, 256, 0, stream>>>(ideg, part, N);
    k_scan_out<<<npart + 1, 256, 0, stream>>>(ideg, part, cursor, N, npart, gcnt, gptr, G);
    k_scatter<<<512, 256, 0, stream>>>(ei, ea, E, Epad, cursor, esrc_s, dst_s, ea_s);

    // ---- Layer 1 (D=64) ----
    k_edge_mfma<64><<<eblk64, 256, 0, stream>>>(
        x_bf, ea_s, esrc_s, dst_s, webf1, be1, aggrA, E);
    k_node_mfma<64, true><<<nblk64, 256, 0, stream>>>(aggrA, wnbf1, bnb1, g1, b1, rm1, rv1,
                                                      h_bf, aggrB, N);

    // ---- Layer 2 (D=256) ----
    k_edge_mfma<256><<<eblk256, 256, 0, stream>>>(
        h_bf, ea_s, esrc_s, dst_s, webf2, be2, aggrB, E);
    k_node_mfma<256, true><<<nblk64, 256, 0, stream>>>(aggrB, wnbf2, bnb2, g2, b2, rm2, rv2,
                                                       h_bf, aggrA, N);

    // ---- Layer 3 (D=256) ----
    k_edge_mfma<256><<<eblk256, 256, 0, stream>>>(
        h_bf, ea_s, esrc_s, dst_s, webf3, be3, aggrA, E);
    k_node_mfma<256, false><<<nblk64, 256, 0, stream>>>(aggrA, wnbf3, bnb3, g3, b3, rm3, rv3,
                                                        h_bf, (float*)nullptr, N);

    // ---- Fused pool + head ----
    k_pool_head<<<G, 256, 0, stream>>>(h_bf, gptr, w4p, b4, w5, b5, (float*)d_out);
}

// Round 15
// 261.768 us; speedup vs baseline: 1.0719x; 1.0719x over previous
//
#include <hip/hip_runtime.h>
#include <hip/hip_bf16.h>
#include <math.h>

// ---------------------------------------------------------------------------
// GINE model: 3x (GINEConv + BN + ReLU) -> global mean pool -> MLP -> sigmoid
// Round 15: round-13 edge kernel (1 tile/wave, VGPR 84 — occupancy beats
// prologue amortization, proven r7/r14) + round-14 fused preprocessing
// (12 dispatches) and streamed pool_head.
// ---------------------------------------------------------------------------

typedef __attribute__((ext_vector_type(8))) short short8v;
typedef __attribute__((ext_vector_type(4))) float f32x4;
typedef __attribute__((ext_vector_type(4))) unsigned short us4;
typedef __attribute__((ext_vector_type(8))) unsigned short us8;

static __device__ __forceinline__ float bf2f(unsigned short u) {
    union { unsigned int u32; float f; } c; c.u32 = ((unsigned int)u) << 16; return c.f;
}
static __device__ __forceinline__ unsigned short f2bf(float f) {
    union { float f; unsigned int u; } c; c.f = f;
    unsigned int lsb = (c.u >> 16) & 1u;
    c.u += 0x7fffu + lsb;
    return (unsigned short)(c.u >> 16);
}

__global__ void k_zero_i(int* __restrict__ p, int n) {
    int i = blockIdx.x * blockDim.x + threadIdx.x;
    int st = gridDim.x * blockDim.x;
    for (; i < n; i += st) p[i] = 0;
}

// merged: dst histogram (blocks 0..511), batch histogram (512..639),
// weight/x prep (blocks 640..)
__global__ void k_pre1(const int* __restrict__ dst, int E,
                       const int* __restrict__ batch, int N,
                       int* __restrict__ ideg, int* __restrict__ gcnt,
                       const float* __restrict__ we1, const float* __restrict__ we2,
                       const float* __restrict__ we3, const float* __restrict__ wn1,
                       const float* __restrict__ wn2, const float* __restrict__ wn3,
                       const float* __restrict__ w4, const float* __restrict__ x,
                       unsigned short* __restrict__ webf1, unsigned short* __restrict__ webf2,
                       unsigned short* __restrict__ webf3, unsigned short* __restrict__ wnbf1,
                       unsigned short* __restrict__ wnbf2, unsigned short* __restrict__ wnbf3,
                       float* __restrict__ w4p, unsigned short* __restrict__ x_bf,
                       float* __restrict__ aggrA, int n16) {
    int b = blockIdx.x;
    if (b < 512) {
        int i = b * 256 + threadIdx.x, st = 512 * 256;
        for (; i < E; i += st) atomicAdd(&ideg[dst[i]], 1);
        return;
    }
    if (b < 640) {
        int i = (b - 512) * 256 + threadIdx.x, st = 128 * 256;
        for (; i < N; i += st) atomicAdd(&gcnt[batch[i]], 1);
        return;
    }
    int idx = (b - 640) * 256 + threadIdx.x;
    if (idx >= 49664) {
        int i = idx - 49664;
        if (i < n16) {
            int n = i >> 4, j = i & 15;
            float4 t = *(const float4*)(x + (size_t)n * 64 + j * 4);
            ((float4*)aggrA)[i] = t;
            us4 o;
            o.x = f2bf(x[(size_t)n * 64 + j]);
            o.y = f2bf(x[(size_t)n * 64 + 16 + j]);
            o.z = f2bf(x[(size_t)n * 64 + 32 + j]);
            o.w = f2bf(x[(size_t)n * 64 + 48 + j]);
            *(us4*)(x_bf + (size_t)n * 64 + j * 4) = o;
        }
        return;
    }
    const float* s; unsigned short* d; int rel;
    if (idx < 512)        { s = we1; d = webf1; rel = idx; }
    else if (idx < 2560)  { s = we2; d = webf2; rel = idx - 512; }
    else if (idx < 4608)  { s = we3; d = webf3; rel = idx - 2560; }
    else if (idx < 8704)  { s = wn1; d = wnbf1; rel = idx - 4608; }
    else if (idx < 25088) { s = wn2; d = wnbf2; rel = idx - 8704; }
    else if (idx < 41472) { s = wn3; d = wnbf3; rel = idx - 25088; }
    else {
        // w4p[j][k] = w4[j][chan(k)]  (row-major, permuted k)
        int rel2 = idx - 41472;            // [0, 8192)
        int j = rel2 >> 6;
        int k0 = (rel2 & 63) * 4;
        float4 o;
        float vv[4];
#pragma unroll
        for (int i = 0; i < 4; ++i) {
            int k = k0 + i;
            int ck = (k & 0xC0) | (((k & 3) * 16) + ((k & 63) >> 2));
            vv[i] = w4[j * 256 + ck];
        }
        o.x = vv[0]; o.y = vv[1]; o.z = vv[2]; o.w = vv[3];
        *(float4*)(w4p + j * 256 + k0) = o;
        return;
    }
    float4 t = ((const float4*)s)[rel];
    us4 o; o.x = f2bf(t.x); o.y = f2bf(t.y); o.z = f2bf(t.z); o.w = f2bf(t.w);
    ((us4*)d)[rel] = o;
}

// per-block sums of ideg
__global__ __launch_bounds__(256) void k_scan_part(const int* __restrict__ in,
                                                   int* __restrict__ part, int n) {
    __shared__ int wtot[4];
    const int tid = threadIdx.x, lane = tid & 63, wv = tid >> 6;
    int i = blockIdx.x * 256 + tid;
    int s = (i < n) ? in[i] : 0;
#pragma unroll
    for (int off = 1; off < 64; off <<= 1) s += __shfl_xor(s, off);
    if (lane == 0) wtot[wv] = s;
    __syncthreads();
    if (tid == 0) part[blockIdx.x] = wtot[0] + wtot[1] + wtot[2] + wtot[3];
}

// blocks 0..npart-1: cursor = exclusive scan of ideg (block offset computed
// in-block from part[]); block npart: gptr = exclusive scan of gcnt (1 wave).
__global__ __launch_bounds__(256) void k_scan_out(const int* __restrict__ in,
                                                  const int* __restrict__ part,
                                                  int* __restrict__ cursor, int n, int npart,
                                                  const int* __restrict__ gcnt,
                                                  int* __restrict__ gptr, int G) {
    const int tid = threadIdx.x, lane = tid & 63, wv = tid >> 6;
    if ((int)blockIdx.x == npart) {
        if (tid < 64) {
            int run = 0;
            for (int c = 0; c < G; c += 64) {
                int v = gcnt[c + lane];
                int s = v;
#pragma unroll
                for (int off = 1; off < 64; off <<= 1) {
                    int t = __shfl_up(s, off);
                    if (lane >= off) s += t;
                }
                gptr[c + lane] = run + s - v;
                run += __shfl(s, 63);
            }
            if (lane == 0) gptr[G] = run;
        }
        return;
    }
    __shared__ int wtot[4];
    const int bid = blockIdx.x;
    int p = 0;
    if (lane < bid) p = part[lane];
    if (lane + 64 < bid) p += part[lane + 64];     // npart <= 128
#pragma unroll
    for (int off = 1; off < 64; off <<= 1) p += __shfl_xor(p, off);
    int i = bid * 256 + tid;
    int v = (i < n) ? in[i] : 0;
    int s = v;
#pragma unroll
    for (int off = 1; off < 64; off <<= 1) {
        int t = __shfl_up(s, off);
        if (lane >= off) s += t;
    }
    if (lane == 63) wtot[wv] = s;
    __syncthreads();
    int woff = 0;
    for (int k = 0; k < wv; ++k) woff += wtot[k];
    if (i < n) cursor[i] = p + woff + s - v;
}

// bucket edges by dst; convert+write ea row at pos (fused permute); pad tails
__global__ void k_scatter(const int* __restrict__ ei, const float* __restrict__ ea,
                          int E, int Epad, int* __restrict__ cursor,
                          int* __restrict__ esrc_s, int* __restrict__ dst_s,
                          unsigned short* __restrict__ ea_s) {
    int i = blockIdx.x * blockDim.x + threadIdx.x;
    int st = gridDim.x * blockDim.x;
    for (int k = i; k < E; k += st) {
        int d = ei[E + k];
        int pos = atomicAdd(&cursor[d], 1);
        esrc_s[pos] = ei[k];
        dst_s[pos] = d;
        const float4* sp = (const float4*)(ea + (size_t)k * 32);
        unsigned short* dp = ea_s + (size_t)pos * 32;
#pragma unroll
        for (int h = 0; h < 4; ++h) {
            float4 a = sp[2 * h], b = sp[2 * h + 1];
            us8 o;
            o[0] = f2bf(a.x); o[1] = f2bf(a.y); o[2] = f2bf(a.z); o[3] = f2bf(a.w);
            o[4] = f2bf(b.x); o[5] = f2bf(b.y); o[6] = f2bf(b.z); o[7] = f2bf(b.w);
            *(us8*)(dp + h * 8) = o;
        }
    }
    if (i < Epad + 64 - E) {
        dst_s[E + i] = -1;
        if (i < Epad - E) {
            esrc_s[E + i] = 0;
            us4 z = {0, 0, 0, 0};
            us4* p = (us4*)(ea_s + (size_t)(E + i) * 32);
#pragma unroll
            for (int q = 0; q < 8; ++q) p[q] = z;
        }
    }
}

// ---------------------------------------------------------------------------
// Edge kernel (round-13 exact: 1 tile/wave). Permuted-h 8B gathers; tile-wide
// inclusive prefix; scalar segment walk with telescoping diff; 4 contiguous
// atomics per segment from lhi==0 lanes.
// aggr must be pre-initialized with the self term (f32, natural layout).
// ---------------------------------------------------------------------------
template<int D>
__global__ __launch_bounds__(256) void k_edge_mfma(
    const unsigned short* __restrict__ hbf,   // [N][D] bf16, PERMUTED layout
    const unsigned short* __restrict__ ea_s,  // [Epad][32] bf16, CSR order
    const int* __restrict__ esrc_s,           // [Epad]
    const int* __restrict__ dst_s,            // [Epad+64], tail = -1
    const unsigned short* __restrict__ webf,  // [D][32] bf16, natural rows
    const float* __restrict__ be,             // [D]
    float* __restrict__ aggr,                 // [N][D] f32, natural layout
    int E)
{
    const int tid = threadIdx.x;
    const int lane = tid & 63;
    const int w = tid >> 6;
    const int l15 = lane & 15;
    const int lhi = lane >> 4;

    const int wavetile = (D == 256) ? (int)blockIdx.x : ((int)blockIdx.x * 4 + w);
    const int colbase  = (D == 256) ? (w * 64) : 0;
    const int e0 = wavetile * 64;
    if (e0 >= E) return;

    const int dstreg = dst_s[e0 + lane];      // lane = row

    int4 src4[4];
#pragma unroll
    for (int q = 0; q < 4; ++q)
        src4[q] = *(const int4*)(esrc_s + e0 + q * 16 + lhi * 4);

    short8v afr[4];
#pragma unroll
    for (int q = 0; q < 4; ++q)
        afr[q] = *(const short8v*)(ea_s + (size_t)(e0 + q * 16 + l15) * 32 + lhi * 8);

    short8v bfr[4]; float bias[4];
#pragma unroll
    for (int t = 0; t < 4; ++t) {
        int c = colbase + t * 16 + l15;
        bfr[t] = *(const short8v*)(webf + (size_t)c * 32 + lhi * 8);
        bias[t] = be[c];
    }

    // permuted h-gather: one us4 per fragment row -> channels {t*16+l15}
    us4 hv[4][4];
#pragma unroll
    for (int q = 0; q < 4; ++q) {
        const int sr[4] = {src4[q].x, src4[q].y, src4[q].z, src4[q].w};
#pragma unroll
        for (int i = 0; i < 4; ++i)
            hv[q][i] = *(const us4*)(hbf + (size_t)sr[i] * D + colbase + l15 * 4);
    }

    f32x4 acc[4][4];
#pragma unroll
    for (int q = 0; q < 4; ++q)
#pragma unroll
        for (int t = 0; t < 4; ++t) {
            f32x4 ci; ci[0] = bias[t]; ci[1] = bias[t]; ci[2] = bias[t]; ci[3] = bias[t];
            acc[q][t] = __builtin_amdgcn_mfma_f32_16x16x32_bf16(afr[q], bfr[t], ci, 0, 0, 0);
        }

    // m = relu(el + h_src)
#pragma unroll
    for (int q = 0; q < 4; ++q)
#pragma unroll
        for (int i = 0; i < 4; ++i) {
            us4 h4 = hv[q][i];
#pragma unroll
            for (int t = 0; t < 4; ++t)
                acc[q][t][i] = fmaxf(acc[q][t][i] + bf2f(h4[t]), 0.0f);
        }

    // ---- tile-wide inclusive prefix (in place on acc) ----
    float carry[4] = {0.0f, 0.0f, 0.0f, 0.0f};
#pragma unroll
    for (int q = 0; q < 4; ++q)
#pragma unroll
        for (int t = 0; t < 4; ++t) {
            acc[q][t][1] += acc[q][t][0];
            acc[q][t][2] += acc[q][t][1];
            acc[q][t][3] += acc[q][t][2];
            float g = acc[q][t][3];
            float g1 = __shfl_up(g, 16);
            if (lhi >= 1) g += g1;
            float g2 = __shfl_up(g, 32);
            if (lhi >= 2) g += g2;
            float tqv = __shfl(g, 48 + l15);        // subtile total (lhi=3 incl)
            float excl = g - acc[q][t][3] + carry[t];
            acc[q][t][0] += excl; acc[q][t][1] += excl;
            acc[q][t][2] += excl; acc[q][t][3] += excl;
            carry[t] += tqv;
        }

    // ---- segment-end mask (row = lane; forced end at row 63) ----
    int dnext = __shfl_down(dstreg, 1);
    bool endf = (lane == 63) || (dstreg != dnext);
    unsigned long long mask = __ballot(endf);

    // ---- scalar segment walk with telescoping difference ----
    float prevP[4] = {0.0f, 0.0f, 0.0f, 0.0f};
    while (mask) {
        int r = __builtin_amdgcn_readfirstlane((int)__builtin_ctzll(mask));
        mask &= mask - 1;
        int dseg = __shfl(dstreg, r);
        int sl = ((r >> 2) & 3) * 16 + l15;     // source lane holding row r
        float curP[4];
        switch (((r >> 4) << 2) | (r & 3)) {
#define CASE_QI(Q, I) \
            case ((Q) * 4 + (I)): \
                curP[0] = __shfl(acc[Q][0][I], sl); curP[1] = __shfl(acc[Q][1][I], sl); \
                curP[2] = __shfl(acc[Q][2][I], sl); curP[3] = __shfl(acc[Q][3][I], sl); \
                break;
            CASE_QI(0,0) CASE_QI(0,1) CASE_QI(0,2) CASE_QI(0,3)
            CASE_QI(1,0) CASE_QI(1,1) CASE_QI(1,2) CASE_QI(1,3)
            CASE_QI(2,0) CASE_QI(2,1) CASE_QI(2,2) CASE_QI(2,3)
            CASE_QI(3,0) CASE_QI(3,1) CASE_QI(3,2) CASE_QI(3,3)
#undef CASE_QI
        }
        if (dseg >= 0 && lhi == 0) {
            float* base = aggr + (size_t)dseg * D + colbase + l15;
#pragma unroll
            for (int t = 0; t < 4; ++t)
                atomicAdd(base + t * 16, curP[t] - prevP[t]);
        }
#pragma unroll
        for (int t = 0; t < 4; ++t) prevP[t] = curP[t];
    }
}

// ---------------------------------------------------------------------------
// MFMA node GEMM + BN + ReLU. Natural aggr in/out; h_bf stored PERMUTED via
// two 16B stores per row-fragment.
// ---------------------------------------------------------------------------
template<int K, bool AW>
__global__ __launch_bounds__(256) void k_node_mfma(
    const float* __restrict__ A, const unsigned short* __restrict__ wnbf,
    const float* __restrict__ bnb, const float* __restrict__ g,
    const float* __restrict__ b, const float* __restrict__ rm,
    const float* __restrict__ rv, unsigned short* __restrict__ out,
    float* __restrict__ aggr_out, int N)
{
    const int tid = threadIdx.x;
    const int lane = tid & 63;
    const int w = tid >> 6;
    const int l15 = lane & 15;
    const int lhi = lane >> 4;
    const int row0 = blockIdx.x * 64;
    const int ncol0 = w * 64;

    f32x4 scale[4], shift[4];
    f32x4 acc[4][4];
#pragma unroll
    for (int q = 0; q < 4; ++q) {
        int n0 = ncol0 + q * 16 + lhi * 4;
        float4 gg = *(const float4*)(g + n0);
        float4 rvv = *(const float4*)(rv + n0);
        float4 bb = *(const float4*)(b + n0);
        float4 rmm = *(const float4*)(rm + n0);
        float4 bn = *(const float4*)(bnb + n0);
        f32x4 sc, sh, ci;
        sc[0] = gg.x * rsqrtf(rvv.x + 1e-5f);
        sc[1] = gg.y * rsqrtf(rvv.y + 1e-5f);
        sc[2] = gg.z * rsqrtf(rvv.z + 1e-5f);
        sc[3] = gg.w * rsqrtf(rvv.w + 1e-5f);
        sh[0] = bb.x - rmm.x * sc[0];
        sh[1] = bb.y - rmm.y * sc[1];
        sh[2] = bb.z - rmm.z * sc[2];
        sh[3] = bb.w - rmm.w * sc[3];
        ci[0] = bn.x; ci[1] = bn.y; ci[2] = bn.z; ci[3] = bn.w;
        scale[q] = sc; shift[q] = sh;
#pragma unroll
        for (int r = 0; r < 4; ++r) acc[q][r] = ci;
    }

    for (int k0 = 0; k0 < K; k0 += 32) {
        short8v wfr[4];
#pragma unroll
        for (int q = 0; q < 4; ++q)
            wfr[q] = *(const short8v*)(wnbf + (size_t)(ncol0 + q * 16 + l15) * K + k0 + lhi * 8);
        short8v afr[4];
#pragma unroll
        for (int r = 0; r < 4; ++r) {
            const float* ap = A + (size_t)(row0 + r * 16 + l15) * K + k0 + lhi * 8;
            float4 a0 = ((const float4*)ap)[0];
            float4 a1 = ((const float4*)ap)[1];
            short8v t;
            t[0] = (short)f2bf(a0.x); t[1] = (short)f2bf(a0.y);
            t[2] = (short)f2bf(a0.z); t[3] = (short)f2bf(a0.w);
            t[4] = (short)f2bf(a1.x); t[5] = (short)f2bf(a1.y);
            t[6] = (short)f2bf(a1.z); t[7] = (short)f2bf(a1.w);
            afr[r] = t;
        }
#pragma unroll
        for (int q = 0; q < 4; ++q)
#pragma unroll
            for (int r = 0; r < 4; ++r)
                acc[q][r] = __builtin_amdgcn_mfma_f32_16x16x32_bf16(wfr[q], afr[r], acc[q][r], 0, 0, 0);
    }

#pragma unroll
    for (int r = 0; r < 4; ++r) {
        int m = row0 + r * 16 + l15;
        if (m < N) {
            f32x4 o4[4];
#pragma unroll
            for (int q = 0; q < 4; ++q) {
                int n0 = ncol0 + q * 16 + lhi * 4;
                f32x4 v = acc[q][r];
                f32x4 o;
#pragma unroll
                for (int i = 0; i < 4; ++i)
                    o[i] = fmaxf(v[i] * scale[q][i] + shift[q][i], 0.0f);
                o4[q] = o;
                if (AW) *(f32x4*)(aggr_out + (size_t)m * 256 + n0) = o;
            }
            us8 lo, hi;
#pragma unroll
            for (int q = 0; q < 4; ++q)
#pragma unroll
                for (int i = 0; i < 4; ++i) {
                    int p = i * 4 + q;
                    unsigned short v = f2bf(o4[q][i]);
                    if (p < 8) lo[p] = v; else hi[p - 8] = v;
                }
            *(us8*)(out + (size_t)m * 256 + ncol0 + lhi * 16) = lo;
            *(us8*)(out + (size_t)m * 256 + ncol0 + lhi * 16 + 8) = hi;
        }
    }
}

// Fused global-mean-pool + MLP head (h in PERMUTED bf16; w4p row-major
// with permuted k, so thread j streams its own row with float4).
__global__ __launch_bounds__(256) void k_pool_head(
    const unsigned short* __restrict__ h, const int* __restrict__ gptr,
    const float* __restrict__ w4p, const float* __restrict__ b4,
    const float* __restrict__ w5, const float* __restrict__ b5,
    float* __restrict__ out)
{
    __shared__ float pl[256];
    __shared__ float zs[128];
    const int g = blockIdx.x;
    const int tid = threadIdx.x;
    int beg = gptr[g], end = gptr[g + 1];
    float acc = 0.0f;
    for (int r = beg; r < end; ++r) acc += bf2f(h[(size_t)r * 256 + tid]);
    float cnt = (float)(end - beg);
    pl[tid] = acc / fmaxf(cnt, 1.0f);
    __syncthreads();
    if (tid < 128) {
        float a = b4[tid];
        const float4* wr = (const float4*)(w4p + (size_t)tid * 256);
        for (int k4 = 0; k4 < 64; ++k4) {
            float4 wv = wr[k4];
            int k = k4 * 4;
            a += pl[k] * wv.x + pl[k + 1] * wv.y + pl[k + 2] * wv.z + pl[k + 3] * wv.w;
        }
        zs[tid] = fmaxf(a, 0.0f);
    }
    __syncthreads();
    if (tid < 64) {
        float v = zs[tid] * w5[tid] + zs[tid + 64] * w5[tid + 64];
#pragma unroll
        for (int off = 32; off > 0; off >>= 1) v += __shfl_down(v, off);
        if (tid == 0) out[g] = 1.0f / (1.0f + expf(-(v + b5[0])));
    }
}

extern "C" void kernel_launch(void* const* d_in, const int* in_sizes, int n_in,
                              void* d_out, int out_size, void* d_ws, size_t ws_size,
                              hipStream_t stream)
{
    const float* x    = (const float*)d_in[0];
    const int*   ei   = (const int*)d_in[1];
    const float* ea   = (const float*)d_in[2];
    const int*   batch= (const int*)d_in[3];
    const float* we1  = (const float*)d_in[4];
    const float* be1  = (const float*)d_in[5];
    const float* wn1  = (const float*)d_in[6];
    const float* bnb1 = (const float*)d_in[7];
    const float* we2  = (const float*)d_in[8];
    const float* be2  = (const float*)d_in[9];
    const float* wn2  = (const float*)d_in[10];
    const float* bnb2 = (const float*)d_in[11];
    const float* we3  = (const float*)d_in[12];
    const float* be3  = (const float*)d_in[13];
    const float* wn3  = (const float*)d_in[14];
    const float* bnb3 = (const float*)d_in[15];
    const float* g1 = (const float*)d_in[16];
    const float* b1 = (const float*)d_in[17];
    const float* rm1= (const float*)d_in[18];
    const float* rv1= (const float*)d_in[19];
    const float* g2 = (const float*)d_in[20];
    const float* b2 = (const float*)d_in[21];
    const float* rm2= (const float*)d_in[22];
    const float* rv2= (const float*)d_in[23];
    const float* g3 = (const float*)d_in[24];
    const float* b3 = (const float*)d_in[25];
    const float* rm3= (const float*)d_in[26];
    const float* rv3= (const float*)d_in[27];
    const float* w4 = (const float*)d_in[28];
    const float* b4 = (const float*)d_in[29];
    const float* w5 = (const float*)d_in[30];
    const float* b5 = (const float*)d_in[31];

    const int N = in_sizes[0] / 64;
    const int E = in_sizes[1] / 2;
    const int G = out_size;
    const int Epad = (E + 63) & ~63;
    const int npart = (N + 255) / 256;
    const int n16 = N * 16;

    // ---- workspace layout ----
    float* ws    = (float*)d_ws;
    float* aggrA = ws;                                  // N*256 f32
    float* aggrB = aggrA + (size_t)N * 256;             // N*256 f32
    float* w4p   = aggrB + (size_t)N * 256;             // 128*256
    unsigned short* ea_s  = (unsigned short*)(w4p + 128 * 256);   // Epad*32 bf16
    unsigned short* x_bf  = ea_s + (size_t)Epad * 32;   // N*64 bf16 (permuted)
    unsigned short* h_bf  = x_bf + (size_t)N * 64;      // N*256 bf16 (permuted)
    unsigned short* webf1 = h_bf + (size_t)N * 256;     // 64*32 bf16
    unsigned short* webf2 = webf1 + 64 * 32;            // 256*32
    unsigned short* webf3 = webf2 + 256 * 32;           // 256*32
    unsigned short* wnbf1 = webf3 + 256 * 32;           // 256*64 bf16
    unsigned short* wnbf2 = wnbf1 + 256 * 64;           // 256*256
    unsigned short* wnbf3 = wnbf2 + 256 * 256;          // 256*256
    int* iws    = (int*)(wnbf3 + 256 * 256);
    int* ideg   = iws;                                  // N   (gcnt adjacent!)
    int* gcnt   = ideg + N;                             // G
    int* gptr   = gcnt + G;                             // G+16
    int* cursor = gptr + G + 16;                        // N
    int* esrc_s = cursor + N;                           // Epad
    int* dst_s  = esrc_s + Epad;                        // Epad+64 (tail -1)
    int* part   = dst_s + Epad + 64;                    // npart

    const int nblk64  = (N + 63) / 64;
    const int ntiles  = (E + 63) / 64;
    const int eblk256 = ntiles;                         // 1 tile per block
    const int eblk64  = (ntiles + 3) / 4;               // 1 tile per wave

    // ---- fused preprocessing (5 launches) ----
    k_zero_i<<<64, 256, 0, stream>>>(ideg, N + G);
    k_pre1<<<640 + (49664 + n16 + 255) / 256, 256, 0, stream>>>(
        ei + E, E, batch, N, ideg, gcnt,
        we1, we2, we3, wn1, wn2, wn3, w4, x,
        webf1, webf2, webf3, wnbf1, wnbf2, wnbf3, w4p, x_bf, aggrA, n16);
    k_scan_part<<<npart, 256, 0, stream>>>(ideg, part, N);
    k_scan_out<<<npart + 1, 256, 0, stream>>>(ideg, part, cursor, N, npart, gcnt, gptr, G);
    k_scatter<<<512, 256, 0, stream>>>(ei, ea, E, Epad, cursor, esrc_s, dst_s, ea_s);

    // ---- Layer 1 (D=64) ----
    k_edge_mfma<64><<<eblk64, 256, 0, stream>>>(
        x_bf, ea_s, esrc_s, dst_s, webf1, be1, aggrA, E);
    k_node_mfma<64, true><<<nblk64, 256, 0, stream>>>(aggrA, wnbf1, bnb1, g1, b1, rm1, rv1,
                                                      h_bf, aggrB, N);

    // ---- Layer 2 (D=256) ----
    k_edge_mfma<256><<<eblk256, 256, 0, stream>>>(
        h_bf, ea_s, esrc_s, dst_s, webf2, be2, aggrB, E);
    k_node_mfma<256, true><<<nblk64, 256, 0, stream>>>(aggrB, wnbf2, bnb2, g2, b2, rm2, rv2,
                                                       h_bf, aggrA, N);

    // ---- Layer 3 (D=256) ----
    k_edge_mfma<256><<<eblk256, 256, 0, stream>>>(
        h_bf, ea_s, esrc_s, dst_s, webf3, be3, aggrA, E);
    k_node_mfma<256, false><<<nblk64, 256, 0, stream>>>(aggrA, wnbf3, bnb3, g3, b3, rm3, rv3,
                                                        h_bf, (float*)nullptr, N);

    // ---- Fused pool + head ----
    k_pool_head<<<G, 256, 0, stream>>>(h_bf, gptr, w4p, b4, w5, b5, (float*)d_out);
}